// Round 11
// baseline (340.177 us; speedup 1.0000x reference)
//
#include <hip/hip_runtime.h>

// GCN forward: init(W0'=W_pre@Wc0 merge) -> fill_enc(CSR fill + encoder) ->
// 3x{conv MFMA (inline rsqrt-deg scale), padded-CSR full-row pull-aggregate} -> head.
// N=50000, E=1.6M, D=128, DIN=100, DOUT=40.
// Learned: r7 no device-scope spin barriers; r8 no shfl-broadcast matvec (shfl is an
// LDS-pipe op on CDNA); r9 gather is L3/fabric-delivery-bound -> locality splits neutral.
// r10: aggregate col indices are wave-uniform -> scalar s_load path + SGPR-base gathers.

#define NNODES 50000
#define NEDGES 1600000
#define DINN 100
#define DOUTN 40
#define CAP 96
#define NB1 ((NNODES + 255) / 256)  // 196
#define PDIV 687195u                // (d*PDIV)>>32 == d/6250 for d in [0,50000)
#define NGROUP 391
#define FE_GRID (NGROUP * 24)       // 16 fill + 8 enc per group of 24
#define MTILES ((NNODES + 63) / 64) // 782

typedef __attribute__((ext_vector_type(8))) short short8;
typedef __attribute__((ext_vector_type(4))) float floatx4;

static __device__ __forceinline__ unsigned int f2bf(float f) {
    unsigned int u = __float_as_uint(f);
    return (u + 0x7fffu + ((u >> 16) & 1u)) >> 16;  // RNE
}
static __device__ __forceinline__ float bflo(unsigned int u) { return __uint_as_float(u << 16); }
static __device__ __forceinline__ float bfhi(unsigned int u) { return __uint_as_float(u & 0xffff0000u); }

// ---------------- init: zero cursors + weight transposes + merged W0' + v0 ----------------
__global__ void init_ws(int* __restrict__ cursor, const float* __restrict__ Wpre,
                        const float* __restrict__ Wc, const float* __restrict__ b_pre,
                        unsigned int* __restrict__ Wt, float* __restrict__ v0) {
    int bid = blockIdx.x, tid = threadIdx.x;
    if (bid < NB1) {
        int n = bid * 256 + tid;
        if (n < NNODES) cursor[n] = 0;
    } else if (bid < NB1 + 64) {
        int tt = (bid - NB1) * 256 + tid;  // 2 mats * 8192
        int mm = 2 + (tt >> 13);           // slot 2,3
        int rem = tt & 8191;
        int n = rem >> 6, k2 = rem & 63;
        const float* W = Wc + (size_t)(mm - 1) * 16384;  // Wc1, Wc2
        unsigned int lo = f2bf(W[(2 * k2) * 128 + n]);
        unsigned int hi = f2bf(W[(2 * k2 + 1) * 128 + n]);
        Wt[mm * 8192 + n * 64 + k2] = lo | (hi << 16);
    } else if (bid < NB1 + 96) {
        int t = (bid - NB1 - 64) * 256 + tid;  // 8192: (n, k2) of W0'
        int n = t >> 6, k2 = t & 63;
        const float* wp0 = Wpre + (size_t)(2 * k2) * 128;
        const float* wp1 = wp0 + 128;
        float d0 = 0.f, d1 = 0.f;
#pragma unroll 4
        for (int j = 0; j < 128; j++) {
            float wc = Wc[j * 128 + n];
            d0 += wp0[j] * wc;
            d1 += wp1[j] * wc;
        }
        Wt[8192 + n * 64 + k2] = f2bf(d0) | (f2bf(d1) << 16);
    } else {
        if (tid < 128) {
            float d = 0.f;
#pragma unroll 4
            for (int j = 0; j < 128; j++) d += b_pre[j] * Wc[j * 128 + tid];
            v0[tid] = d;
        }
    }
}

// ---------------- FUSED: partitioned padded-CSR fill + encoder GEMM (bf16 out) ----------------
__global__ __launch_bounds__(256) void fill_enc(const int* __restrict__ src,
                                                const int* __restrict__ dst,
                                                int* __restrict__ cursor,
                                                unsigned short* __restrict__ colp,
                                                const float* __restrict__ x,
                                                const float* __restrict__ W_enc,
                                                const float* __restrict__ b_enc,
                                                unsigned int* __restrict__ C) {
    __shared__ float as[16][DINN];
    int bid = blockIdx.x, tid = threadIdx.x;
    int g = bid / 24, r = bid % 24;
    if (r < 16) {
        int p = bid & 7;
        int chunk = g * 2 + (r >> 3);
        int e0 = chunk * 2048;
#pragma unroll
        for (int k = 0; k < 8; k++) {
            int e = e0 + k * 256 + tid;
            if (e < NEDGES) {
                int d = dst[e];
                if ((int)(((unsigned long long)(unsigned)d * PDIV) >> 32) == p) {
                    int s = src[e];
                    int pos = atomicAdd(&cursor[d], 1);
                    if (pos < CAP) colp[(size_t)d * CAP + pos] = (unsigned short)s;
                }
            }
        }
    } else {
        int tile = g * 8 + (r - 16);
        int row0 = tile * 16;
        if (row0 >= NNODES) return;
        for (int idx = tid; idx < 16 * DINN; idx += 256) {
            int rr = idx / DINN, k = idx - rr * DINN;
            int row = row0 + rr;
            as[rr][k] = (row < NNODES) ? x[(size_t)row * DINN + k] : 0.0f;
        }
        __syncthreads();
        int c = tid & 63;
        int rg = tid >> 6;
        float acc0[4], acc1[4];
#pragma unroll
        for (int q = 0; q < 4; q++) { acc0[q] = 0.f; acc1[q] = 0.f; }
#pragma unroll 4
        for (int k = 0; k < DINN; k++) {
            float2 wv = *(const float2*)&W_enc[k * 128 + 2 * c];
#pragma unroll
            for (int q = 0; q < 4; q++) {
                float a = as[rg * 4 + q][k];
                acc0[q] += a * wv.x;
                acc1[q] += a * wv.y;
            }
        }
        float2 bb = *(const float2*)&b_enc[2 * c];
#pragma unroll
        for (int q = 0; q < 4; q++) {
            int row = row0 + rg * 4 + q;
            if (row < NNODES)
                C[(size_t)row * 64 + c] = f2bf(acc0[q] + bb.x) | (f2bf(acc1[q] + bb.y) << 16);
        }
    }
}

// ---------------- conv MFMA: C[M,128](bf16) = (A@Bt (+v0)) * rsqrt(deg+1), full-row out ------
template <int BIASV>
__global__ __launch_bounds__(256) void conv_mfma(const unsigned int* __restrict__ A,
                                                 const unsigned int* __restrict__ Bt,
                                                 const int* __restrict__ cursor,
                                                 const float* __restrict__ v0,
                                                 unsigned int* __restrict__ C) {
    __shared__ __align__(16) unsigned char smem[49152];
    int tid = threadIdx.x;
    int row0 = blockIdx.x * 64;
    const int M = NNODES;
    for (int c = tid; c < 1024; c += 256) {
        int rr = c >> 4, c16 = c & 15;
        int grow = row0 + rr;
        uint4 p = (grow < M) ? *(const uint4*)&A[(size_t)grow * 64 + c16 * 4]
                             : make_uint4(0, 0, 0, 0);
        *(uint4*)&smem[(rr * 256 + c16 * 16) ^ ((rr & 7) << 4)] = p;
    }
    for (int c = tid; c < 2048; c += 256) {
        int n = c >> 4, k16 = c & 15;
        uint4 v = *(const uint4*)&Bt[n * 64 + k16 * 4];
        *(uint4*)&smem[16384 + ((n * 256 + k16 * 16) ^ ((n & 7) << 4))] = v;
    }
    __syncthreads();

    int lane = tid & 63, w = tid >> 6;
    int ml = lane & 15, kg = lane >> 4;
    short8 afrag[4];
#pragma unroll
    for (int k0 = 0; k0 < 4; k0++) {
        int rr = w * 16 + ml;
        uint4 t = *(uint4*)&smem[(rr * 256 + k0 * 64 + kg * 16) ^ ((rr & 7) << 4)];
        afrag[k0] = *(short8*)&t;
    }
    float dvq[4];
#pragma unroll
    for (int q = 0; q < 4; q++) {
        int grow = row0 + w * 16 + kg * 4 + q;
        dvq[q] = (grow < M) ? rsqrtf((float)(cursor[grow] + 1)) : 0.f;
    }
#pragma unroll
    for (int n = 0; n < 8; n++) {
        floatx4 acc = {0.f, 0.f, 0.f, 0.f};
#pragma unroll
        for (int k0 = 0; k0 < 4; k0++) {
            int rn = n * 16 + ml;
            uint4 t = *(uint4*)&smem[16384 + ((rn * 256 + k0 * 64 + kg * 16) ^ ((rn & 7) << 4))];
            short8 b = *(short8*)&t;
            acc = __builtin_amdgcn_mfma_f32_16x16x32_bf16(afrag[k0], b, acc, 0, 0, 0);
        }
        int colc = n * 16 + ml;
        float bv = BIASV ? v0[colc] : 0.f;
#pragma unroll
        for (int q = 0; q < 4; q++) {
            int grow = row0 + w * 16 + kg * 4 + q;
            float v = (acc[q] + bv) * dvq[q];
            float other = __shfl_xor(v, 1);
            if (!(lane & 1) && grow < M) {
                C[(size_t)grow * 64 + n * 8 + (ml >> 1)] = f2bf(v) | (f2bf(other) << 16);
            }
        }
    }
}

// ---------------- padded-CSR full-row pull aggregate: one wave per dst row -------------------
// Wave-uniform col indices: row forced to SGPR, cp[j] scalar-loaded, gathers use SGPR base.
// LAST=0: +bias, LN, ReLU -> bf16 packed. LAST=1: +bias -> bf16 packed (no LN).
template <int LAST>
__global__ __launch_bounds__(256) void aggregate(const unsigned int* __restrict__ hw,
                                                 const unsigned short* __restrict__ colp,
                                                 const int* __restrict__ cursor,
                                                 const float* __restrict__ bias,
                                                 const float* __restrict__ g,
                                                 const float* __restrict__ b,
                                                 unsigned int* __restrict__ outp) {
    int lane = threadIdx.x & 63;
    int row = __builtin_amdgcn_readfirstlane(blockIdx.x * 4 + (threadIdx.x >> 6));
    if (row >= NNODES) return;
    int curs = __builtin_amdgcn_readfirstlane(cursor[row]);
    int deg = min(curs, CAP);
    const unsigned short* cp = &colp[(size_t)row * CAP];
    unsigned int su = hw[(size_t)row * 64 + lane];  // self loop (hw pre-scaled by src rsqrt)
    float ax0 = bflo(su), ay0 = bfhi(su);
    float ax1 = 0.f, ay1 = 0.f, ax2 = 0.f, ay2 = 0.f, ax3 = 0.f, ay3 = 0.f;
    int j = 0;
    for (; j + 8 <= deg; j += 8) {
        // uniform indices -> scalar loads; gathers get SGPR base + loop-invariant lane offset
        int s0 = (int)cp[j],     s1 = (int)cp[j + 1];
        int s2 = (int)cp[j + 2], s3 = (int)cp[j + 3];
        int s4 = (int)cp[j + 4], s5 = (int)cp[j + 5];
        int s6 = (int)cp[j + 6], s7 = (int)cp[j + 7];
        unsigned u0 = hw[(size_t)s0 * 64 + lane];
        unsigned u1 = hw[(size_t)s1 * 64 + lane];
        unsigned u2 = hw[(size_t)s2 * 64 + lane];
        unsigned u3 = hw[(size_t)s3 * 64 + lane];
        unsigned u4 = hw[(size_t)s4 * 64 + lane];
        unsigned u5 = hw[(size_t)s5 * 64 + lane];
        unsigned u6 = hw[(size_t)s6 * 64 + lane];
        unsigned u7 = hw[(size_t)s7 * 64 + lane];
        ax0 += bflo(u0); ay0 += bfhi(u0);
        ax1 += bflo(u1); ay1 += bfhi(u1);
        ax2 += bflo(u2); ay2 += bfhi(u2);
        ax3 += bflo(u3); ay3 += bfhi(u3);
        ax0 += bflo(u4); ay0 += bfhi(u4);
        ax1 += bflo(u5); ay1 += bfhi(u5);
        ax2 += bflo(u6); ay2 += bfhi(u6);
        ax3 += bflo(u7); ay3 += bfhi(u7);
    }
    for (; j < deg; ++j) {
        int s = (int)cp[j];
        unsigned u = hw[(size_t)s * 64 + lane];
        ax0 += bflo(u); ay0 += bfhi(u);
    }
    float hx = ax0 + ax1 + ax2 + ax3;
    float hy = ay0 + ay1 + ay2 + ay3;
    float sc = rsqrtf((float)(curs + 1));  // dst-side norm, inline
    float2 bb = *(const float2*)&bias[lane * 2];
    hx = hx * sc + bb.x;
    hy = hy * sc + bb.y;
    if (LAST == 0) {
        float sum = hx + hy;
#pragma unroll
        for (int off = 32; off >= 1; off >>= 1) sum += __shfl_xor(sum, off);
        float mu = sum * (1.0f / 128.0f);
        float dx = hx - mu, dy = hy - mu;
        float vs = dx * dx + dy * dy;
#pragma unroll
        for (int off = 32; off >= 1; off >>= 1) vs += __shfl_xor(vs, off);
        float rstd = rsqrtf(vs * (1.0f / 128.0f) + 1e-5f);
        float2 gg = *(const float2*)&g[lane * 2];
        float2 lb = *(const float2*)&b[lane * 2];
        hx = fmaxf(dx * rstd * gg.x + lb.x, 0.0f);
        hy = fmaxf(dy * rstd * gg.y + lb.y, 0.0f);
    }
    outp[(size_t)row * 64 + lane] = f2bf(hx) | (f2bf(hy) << 16);
}

// ---------------- head: out[M,40] = h[M,128](packed bf16) @ W[128,40] + bias ----------------
__global__ __launch_bounds__(256) void head_gemm(const unsigned int* __restrict__ h,
                                                 const float* __restrict__ W,
                                                 const float* __restrict__ bias,
                                                 float* __restrict__ out, int M) {
    __shared__ float hs[32][128];
    int tid = threadIdx.x;
    int row0 = blockIdx.x * 32;
    for (int idx = tid; idx < 32 * 64; idx += 256) {
        int rr = idx >> 6, c = idx & 63;
        int row = row0 + rr;
        unsigned u = (row < M) ? h[(size_t)row * 64 + c] : 0u;
        hs[rr][2 * c] = bflo(u);
        hs[rr][2 * c + 1] = bfhi(u);
    }
    __syncthreads();
    int d = tid & 63;
    int rg = tid >> 6;
    if (d < DOUTN) {
        float acc[8];
#pragma unroll
        for (int q = 0; q < 8; q++) acc[q] = 0.0f;
#pragma unroll 4
        for (int k = 0; k < 128; k++) {
            float wv = W[k * DOUTN + d];
#pragma unroll
            for (int q = 0; q < 8; q++) acc[q] += hs[rg * 8 + q][k] * wv;
        }
        float bv = bias[d];
#pragma unroll
        for (int q = 0; q < 8; q++) {
            int row = row0 + rg * 8 + q;
            if (row < M) out[(size_t)row * DOUTN + d] = acc[q] + bv;
        }
    }
}

extern "C" void kernel_launch(void* const* d_in, const int* in_sizes, int n_in,
                              void* d_out, int out_size, void* d_ws, size_t ws_size,
                              hipStream_t stream) {
    const float* x = (const float*)d_in[0];
    const int* ei = (const int*)d_in[1];
    const int* esrc = ei;
    const int* edst = ei + NEDGES;
    const float* W_enc = (const float*)d_in[2];
    const float* b_enc = (const float*)d_in[3];
    const float* W_pre = (const float*)d_in[4];
    const float* b_pre = (const float*)d_in[5];
    const float* Wc = (const float*)d_in[6];
    const float* bc = (const float*)d_in[7];
    const float* ln_g = (const float*)d_in[8];
    const float* ln_b = (const float*)d_in[9];
    const float* W_head = (const float*)d_in[10];
    const float* b_head = (const float*)d_in[11];
    float* out = (float*)d_out;

    char* ws = (char*)d_ws;
    const size_t packBytes = (size_t)NNODES * 64 * 4;  // 12.8 MB packed bf16
    size_t off = 0;
    unsigned int* F1 = (unsigned int*)(ws + off); off += packBytes;  // enc out
    unsigned int* F2 = (unsigned int*)(ws + off); off += packBytes;  // h / final h
    unsigned int* hw = (unsigned int*)(ws + off); off += packBytes;  // transformed
    int* cursor = (int*)(ws + off); off += (size_t)NNODES * 4;
    unsigned int* Wt = (unsigned int*)(ws + off); off += (size_t)4 * 8192 * 4;
    float* v0 = (float*)(ws + off); off += 512;
    unsigned short* colp = (unsigned short*)(ws + off); off += (size_t)NNODES * CAP * 2;

    // ---- init: zero cursors + transposes + W0' + v0 ----
    init_ws<<<NB1 + 97, 256, 0, stream>>>(cursor, W_pre, Wc, b_pre, Wt, v0);

    // ---- padded-CSR fill hidden under encoder GEMM ----
    fill_enc<<<FE_GRID, 256, 0, stream>>>(esrc, edst, cursor, colp, x, W_enc, b_enc, F1);

    // ---- layer 0: merged (W_pre@Wc0) transform from enc output ----
    conv_mfma<1><<<MTILES, 256, 0, stream>>>(F1, Wt + 8192, cursor, v0, hw);
    aggregate<0><<<(NNODES + 3) / 4, 256, 0, stream>>>(hw, colp, cursor, bc, ln_g, ln_b, F2);

    // ---- layer 1 ----
    conv_mfma<0><<<MTILES, 256, 0, stream>>>(F2, Wt + 2 * 8192, cursor, nullptr, hw);
    aggregate<0><<<(NNODES + 3) / 4, 256, 0, stream>>>(hw, colp, cursor, bc + 128, ln_g + 128,
                                                       ln_b + 128, F2);

    // ---- layer 2 (no LN) ----
    conv_mfma<0><<<MTILES, 256, 0, stream>>>(F2, Wt + 3 * 8192, cursor, nullptr, hw);
    aggregate<1><<<(NNODES + 3) / 4, 256, 0, stream>>>(hw, colp, cursor, bc + 256, nullptr,
                                                       nullptr, F2);

    // ---- head ----
    head_gemm<<<(NNODES + 31) / 32, 256, 0, stream>>>(F2, W_head, b_head, out, NNODES);
}

// Round 12
// 326.306 us; speedup vs baseline: 1.0425x; 1.0425x over previous
//
#include <hip/hip_runtime.h>

// GCN forward: init(W0'=W_pre@Wc0 merge) -> fill_enc(CSR fill + encoder) ->
// 3x{conv MFMA (inline rsqrt-deg scale), padded-CSR full-row pull-aggregate} -> head.
// N=50000, E=1.6M, D=128, DIN=100, DOUT=40.
// Learned: r7 no device-scope spin barriers; r8 no shfl-broadcast matvec (shfl is an
// LDS-pipe op on CDNA); r9 gather is L3-delivery-bound -> locality splits neutral;
// r11 scalar s_load path for ushort indices regresses (no sub-dword scalar loads).
// Aggregate floor: 422 MB/layer random row-gather @ ~7.4 TB/s effective.

#define NNODES 50000
#define NEDGES 1600000
#define DINN 100
#define DOUTN 40
#define CAP 96
#define NB1 ((NNODES + 255) / 256)  // 196
#define PDIV 687195u                // (d*PDIV)>>32 == d/6250 for d in [0,50000)
#define NGROUP 391
#define FE_GRID (NGROUP * 24)       // 16 fill + 8 enc per group of 24
#define MTILES ((NNODES + 63) / 64) // 782

typedef __attribute__((ext_vector_type(8))) short short8;
typedef __attribute__((ext_vector_type(4))) float floatx4;

static __device__ __forceinline__ unsigned int f2bf(float f) {
    unsigned int u = __float_as_uint(f);
    return (u + 0x7fffu + ((u >> 16) & 1u)) >> 16;  // RNE
}
static __device__ __forceinline__ float bflo(unsigned int u) { return __uint_as_float(u << 16); }
static __device__ __forceinline__ float bfhi(unsigned int u) { return __uint_as_float(u & 0xffff0000u); }

// ---------------- init: zero cursors + weight transposes + merged W0' + v0 ----------------
__global__ void init_ws(int* __restrict__ cursor, const float* __restrict__ Wpre,
                        const float* __restrict__ Wc, const float* __restrict__ b_pre,
                        unsigned int* __restrict__ Wt, float* __restrict__ v0) {
    int bid = blockIdx.x, tid = threadIdx.x;
    if (bid < NB1) {
        int n = bid * 256 + tid;
        if (n < NNODES) cursor[n] = 0;
    } else if (bid < NB1 + 64) {
        int tt = (bid - NB1) * 256 + tid;  // 2 mats * 8192
        int mm = 2 + (tt >> 13);           // slot 2,3
        int rem = tt & 8191;
        int n = rem >> 6, k2 = rem & 63;
        const float* W = Wc + (size_t)(mm - 1) * 16384;  // Wc1, Wc2
        unsigned int lo = f2bf(W[(2 * k2) * 128 + n]);
        unsigned int hi = f2bf(W[(2 * k2 + 1) * 128 + n]);
        Wt[mm * 8192 + n * 64 + k2] = lo | (hi << 16);
    } else if (bid < NB1 + 96) {
        int t = (bid - NB1 - 64) * 256 + tid;  // 8192: (n, k2) of W0'
        int n = t >> 6, k2 = t & 63;
        const float* wp0 = Wpre + (size_t)(2 * k2) * 128;
        const float* wp1 = wp0 + 128;
        float d0 = 0.f, d1 = 0.f;
#pragma unroll 4
        for (int j = 0; j < 128; j++) {
            float wc = Wc[j * 128 + n];
            d0 += wp0[j] * wc;
            d1 += wp1[j] * wc;
        }
        Wt[8192 + n * 64 + k2] = f2bf(d0) | (f2bf(d1) << 16);
    } else {
        if (tid < 128) {
            float d = 0.f;
#pragma unroll 4
            for (int j = 0; j < 128; j++) d += b_pre[j] * Wc[j * 128 + tid];
            v0[tid] = d;
        }
    }
}

// ---------------- FUSED: partitioned padded-CSR fill + encoder GEMM (bf16 out) ----------------
__global__ __launch_bounds__(256) void fill_enc(const int* __restrict__ src,
                                                const int* __restrict__ dst,
                                                int* __restrict__ cursor,
                                                unsigned short* __restrict__ colp,
                                                const float* __restrict__ x,
                                                const float* __restrict__ W_enc,
                                                const float* __restrict__ b_enc,
                                                unsigned int* __restrict__ C) {
    __shared__ float as[16][DINN];
    int bid = blockIdx.x, tid = threadIdx.x;
    int g = bid / 24, r = bid % 24;
    if (r < 16) {
        int p = bid & 7;
        int chunk = g * 2 + (r >> 3);
        int e0 = chunk * 2048;
#pragma unroll
        for (int k = 0; k < 8; k++) {
            int e = e0 + k * 256 + tid;
            if (e < NEDGES) {
                int d = dst[e];
                if ((int)(((unsigned long long)(unsigned)d * PDIV) >> 32) == p) {
                    int s = src[e];
                    int pos = atomicAdd(&cursor[d], 1);
                    if (pos < CAP) colp[(size_t)d * CAP + pos] = (unsigned short)s;
                }
            }
        }
    } else {
        int tile = g * 8 + (r - 16);
        int row0 = tile * 16;
        if (row0 >= NNODES) return;
        for (int idx = tid; idx < 16 * DINN; idx += 256) {
            int rr = idx / DINN, k = idx - rr * DINN;
            int row = row0 + rr;
            as[rr][k] = (row < NNODES) ? x[(size_t)row * DINN + k] : 0.0f;
        }
        __syncthreads();
        int c = tid & 63;
        int rg = tid >> 6;
        float acc0[4], acc1[4];
#pragma unroll
        for (int q = 0; q < 4; q++) { acc0[q] = 0.f; acc1[q] = 0.f; }
#pragma unroll 4
        for (int k = 0; k < DINN; k++) {
            float2 wv = *(const float2*)&W_enc[k * 128 + 2 * c];
#pragma unroll
            for (int q = 0; q < 4; q++) {
                float a = as[rg * 4 + q][k];
                acc0[q] += a * wv.x;
                acc1[q] += a * wv.y;
            }
        }
        float2 bb = *(const float2*)&b_enc[2 * c];
#pragma unroll
        for (int q = 0; q < 4; q++) {
            int row = row0 + rg * 4 + q;
            if (row < NNODES)
                C[(size_t)row * 64 + c] = f2bf(acc0[q] + bb.x) | (f2bf(acc1[q] + bb.y) << 16);
        }
    }
}

// ---------------- conv MFMA: C[M,128](bf16) = (A@Bt (+v0)) * rsqrt(deg+1), full-row out ------
template <int BIASV>
__global__ __launch_bounds__(256) void conv_mfma(const unsigned int* __restrict__ A,
                                                 const unsigned int* __restrict__ Bt,
                                                 const int* __restrict__ cursor,
                                                 const float* __restrict__ v0,
                                                 unsigned int* __restrict__ C) {
    __shared__ __align__(16) unsigned char smem[49152];
    int tid = threadIdx.x;
    int row0 = blockIdx.x * 64;
    const int M = NNODES;
    for (int c = tid; c < 1024; c += 256) {
        int rr = c >> 4, c16 = c & 15;
        int grow = row0 + rr;
        uint4 p = (grow < M) ? *(const uint4*)&A[(size_t)grow * 64 + c16 * 4]
                             : make_uint4(0, 0, 0, 0);
        *(uint4*)&smem[(rr * 256 + c16 * 16) ^ ((rr & 7) << 4)] = p;
    }
    for (int c = tid; c < 2048; c += 256) {
        int n = c >> 4, k16 = c & 15;
        uint4 v = *(const uint4*)&Bt[n * 64 + k16 * 4];
        *(uint4*)&smem[16384 + ((n * 256 + k16 * 16) ^ ((n & 7) << 4))] = v;
    }
    __syncthreads();

    int lane = tid & 63, w = tid >> 6;
    int ml = lane & 15, kg = lane >> 4;
    short8 afrag[4];
#pragma unroll
    for (int k0 = 0; k0 < 4; k0++) {
        int rr = w * 16 + ml;
        uint4 t = *(uint4*)&smem[(rr * 256 + k0 * 64 + kg * 16) ^ ((rr & 7) << 4)];
        afrag[k0] = *(short8*)&t;
    }
    float dvq[4];
#pragma unroll
    for (int q = 0; q < 4; q++) {
        int grow = row0 + w * 16 + kg * 4 + q;
        dvq[q] = (grow < M) ? rsqrtf((float)(cursor[grow] + 1)) : 0.f;
    }
#pragma unroll
    for (int n = 0; n < 8; n++) {
        floatx4 acc = {0.f, 0.f, 0.f, 0.f};
#pragma unroll
        for (int k0 = 0; k0 < 4; k0++) {
            int rn = n * 16 + ml;
            uint4 t = *(uint4*)&smem[16384 + ((rn * 256 + k0 * 64 + kg * 16) ^ ((rn & 7) << 4))];
            short8 b = *(short8*)&t;
            acc = __builtin_amdgcn_mfma_f32_16x16x32_bf16(afrag[k0], b, acc, 0, 0, 0);
        }
        int colc = n * 16 + ml;
        float bv = BIASV ? v0[colc] : 0.f;
#pragma unroll
        for (int q = 0; q < 4; q++) {
            int grow = row0 + w * 16 + kg * 4 + q;
            float v = (acc[q] + bv) * dvq[q];
            float other = __shfl_xor(v, 1);
            if (!(lane & 1) && grow < M) {
                C[(size_t)grow * 64 + n * 8 + (ml >> 1)] = f2bf(v) | (f2bf(other) << 16);
            }
        }
    }
}

// ---------------- padded-CSR full-row pull aggregate: one wave per dst row -------------------
// LAST=0: +bias, LN, ReLU -> bf16 packed. LAST=1: +bias -> bf16 packed (no LN).
template <int LAST>
__global__ __launch_bounds__(256) void aggregate(const unsigned int* __restrict__ hw,
                                                 const unsigned short* __restrict__ colp,
                                                 const int* __restrict__ cursor,
                                                 const float* __restrict__ bias,
                                                 const float* __restrict__ g,
                                                 const float* __restrict__ b,
                                                 unsigned int* __restrict__ outp) {
    int row = blockIdx.x * 4 + (threadIdx.x >> 6);
    int lane = threadIdx.x & 63;
    if (row >= NNODES) return;
    int curs = cursor[row];
    int deg = min(curs, CAP);
    const unsigned short* cp = &colp[(size_t)row * CAP];
    unsigned int su = hw[(size_t)row * 64 + lane];  // self loop (hw pre-scaled by src rsqrt)
    float ax0 = bflo(su), ay0 = bfhi(su);
    float ax1 = 0.f, ay1 = 0.f, ax2 = 0.f, ay2 = 0.f, ax3 = 0.f, ay3 = 0.f;
    for (int j0 = 0; j0 < deg; j0 += 64) {
        int idx = j0 + lane;
        int myc = (idx < deg) ? (int)cp[idx] : 0;
        int cnt = min(64, deg - j0);
        int j = 0;
        for (; j + 8 <= cnt; j += 8) {
            int s0 = __shfl(myc, j),     s1 = __shfl(myc, j + 1);
            int s2 = __shfl(myc, j + 2), s3 = __shfl(myc, j + 3);
            int s4 = __shfl(myc, j + 4), s5 = __shfl(myc, j + 5);
            int s6 = __shfl(myc, j + 6), s7 = __shfl(myc, j + 7);
            unsigned u0 = hw[(size_t)s0 * 64 + lane];
            unsigned u1 = hw[(size_t)s1 * 64 + lane];
            unsigned u2 = hw[(size_t)s2 * 64 + lane];
            unsigned u3 = hw[(size_t)s3 * 64 + lane];
            unsigned u4 = hw[(size_t)s4 * 64 + lane];
            unsigned u5 = hw[(size_t)s5 * 64 + lane];
            unsigned u6 = hw[(size_t)s6 * 64 + lane];
            unsigned u7 = hw[(size_t)s7 * 64 + lane];
            ax0 += bflo(u0); ay0 += bfhi(u0);
            ax1 += bflo(u1); ay1 += bfhi(u1);
            ax2 += bflo(u2); ay2 += bfhi(u2);
            ax3 += bflo(u3); ay3 += bfhi(u3);
            ax0 += bflo(u4); ay0 += bfhi(u4);
            ax1 += bflo(u5); ay1 += bfhi(u5);
            ax2 += bflo(u6); ay2 += bfhi(u6);
            ax3 += bflo(u7); ay3 += bfhi(u7);
        }
        for (; j < cnt; ++j) {
            int s = __shfl(myc, j);
            unsigned u = hw[(size_t)s * 64 + lane];
            ax0 += bflo(u); ay0 += bfhi(u);
        }
    }
    float hx = ax0 + ax1 + ax2 + ax3;
    float hy = ay0 + ay1 + ay2 + ay3;
    float sc = rsqrtf((float)(curs + 1));  // dst-side norm, inline
    float2 bb = *(const float2*)&bias[lane * 2];
    hx = hx * sc + bb.x;
    hy = hy * sc + bb.y;
    if (LAST == 0) {
        float sum = hx + hy;
#pragma unroll
        for (int off = 32; off >= 1; off >>= 1) sum += __shfl_xor(sum, off);
        float mu = sum * (1.0f / 128.0f);
        float dx = hx - mu, dy = hy - mu;
        float vs = dx * dx + dy * dy;
#pragma unroll
        for (int off = 32; off >= 1; off >>= 1) vs += __shfl_xor(vs, off);
        float rstd = rsqrtf(vs * (1.0f / 128.0f) + 1e-5f);
        float2 gg = *(const float2*)&g[lane * 2];
        float2 lb = *(const float2*)&b[lane * 2];
        hx = fmaxf(dx * rstd * gg.x + lb.x, 0.0f);
        hy = fmaxf(dy * rstd * gg.y + lb.y, 0.0f);
    }
    outp[(size_t)row * 64 + lane] = f2bf(hx) | (f2bf(hy) << 16);
}

// ---------------- head: out[M,40] = h[M,128](packed bf16) @ W[128,40] + bias ----------------
__global__ __launch_bounds__(256) void head_gemm(const unsigned int* __restrict__ h,
                                                 const float* __restrict__ W,
                                                 const float* __restrict__ bias,
                                                 float* __restrict__ out, int M) {
    __shared__ float hs[32][128];
    int tid = threadIdx.x;
    int row0 = blockIdx.x * 32;
    for (int idx = tid; idx < 32 * 64; idx += 256) {
        int rr = idx >> 6, c = idx & 63;
        int row = row0 + rr;
        unsigned u = (row < M) ? h[(size_t)row * 64 + c] : 0u;
        hs[rr][2 * c] = bflo(u);
        hs[rr][2 * c + 1] = bfhi(u);
    }
    __syncthreads();
    int d = tid & 63;
    int rg = tid >> 6;
    if (d < DOUTN) {
        float acc[8];
#pragma unroll
        for (int q = 0; q < 8; q++) acc[q] = 0.0f;
#pragma unroll 4
        for (int k = 0; k < 128; k++) {
            float wv = W[k * DOUTN + d];
#pragma unroll
            for (int q = 0; q < 8; q++) acc[q] += hs[rg * 8 + q][k] * wv;
        }
        float bv = bias[d];
#pragma unroll
        for (int q = 0; q < 8; q++) {
            int row = row0 + rg * 8 + q;
            if (row < M) out[(size_t)row * DOUTN + d] = acc[q] + bv;
        }
    }
}

extern "C" void kernel_launch(void* const* d_in, const int* in_sizes, int n_in,
                              void* d_out, int out_size, void* d_ws, size_t ws_size,
                              hipStream_t stream) {
    const float* x = (const float*)d_in[0];
    const int* ei = (const int*)d_in[1];
    const int* esrc = ei;
    const int* edst = ei + NEDGES;
    const float* W_enc = (const float*)d_in[2];
    const float* b_enc = (const float*)d_in[3];
    const float* W_pre = (const float*)d_in[4];
    const float* b_pre = (const float*)d_in[5];
    const float* Wc = (const float*)d_in[6];
    const float* bc = (const float*)d_in[7];
    const float* ln_g = (const float*)d_in[8];
    const float* ln_b = (const float*)d_in[9];
    const float* W_head = (const float*)d_in[10];
    const float* b_head = (const float*)d_in[11];
    float* out = (float*)d_out;

    char* ws = (char*)d_ws;
    const size_t packBytes = (size_t)NNODES * 64 * 4;  // 12.8 MB packed bf16
    size_t off = 0;
    unsigned int* F1 = (unsigned int*)(ws + off); off += packBytes;  // enc out
    unsigned int* F2 = (unsigned int*)(ws + off); off += packBytes;  // h / final h
    unsigned int* hw = (unsigned int*)(ws + off); off += packBytes;  // transformed
    int* cursor = (int*)(ws + off); off += (size_t)NNODES * 4;
    unsigned int* Wt = (unsigned int*)(ws + off); off += (size_t)4 * 8192 * 4;
    float* v0 = (float*)(ws + off); off += 512;
    unsigned short* colp = (unsigned short*)(ws + off); off += (size_t)NNODES * CAP * 2;

    // ---- init: zero cursors + transposes + W0' + v0 ----
    init_ws<<<NB1 + 97, 256, 0, stream>>>(cursor, W_pre, Wc, b_pre, Wt, v0);

    // ---- padded-CSR fill hidden under encoder GEMM ----
    fill_enc<<<FE_GRID, 256, 0, stream>>>(esrc, edst, cursor, colp, x, W_enc, b_enc, F1);

    // ---- layer 0: merged (W_pre@Wc0) transform from enc output ----
    conv_mfma<1><<<MTILES, 256, 0, stream>>>(F1, Wt + 8192, cursor, v0, hw);
    aggregate<0><<<(NNODES + 3) / 4, 256, 0, stream>>>(hw, colp, cursor, bc, ln_g, ln_b, F2);

    // ---- layer 1 ----
    conv_mfma<0><<<MTILES, 256, 0, stream>>>(F2, Wt + 2 * 8192, cursor, nullptr, hw);
    aggregate<0><<<(NNODES + 3) / 4, 256, 0, stream>>>(hw, colp, cursor, bc + 128, ln_g + 128,
                                                       ln_b + 128, F2);

    // ---- layer 2 (no LN) ----
    conv_mfma<0><<<MTILES, 256, 0, stream>>>(F2, Wt + 3 * 8192, cursor, nullptr, hw);
    aggregate<1><<<(NNODES + 3) / 4, 256, 0, stream>>>(hw, colp, cursor, bc + 256, nullptr,
                                                       nullptr, F2);

    // ---- head ----
    head_gemm<<<(NNODES + 31) / 32, 256, 0, stream>>>(F2, W_head, b_head, out, NNODES);
}